// Round 6
// baseline (251.528 us; speedup 1.0000x reference)
//
#include <hip/hip_runtime.h>
#include <hip/hip_bf16.h>

#define N_ATOMS 32768

typedef __attribute__((ext_vector_type(4))) float f32x4;
typedef __attribute__((ext_vector_type(8))) short bf16x8;
typedef unsigned short u16;

__device__ __forceinline__ u16 f2b(float f) {
    union { __hip_bfloat16 b; u16 u; } c;
    c.b = __float2bfloat16(f);
    return c.u;
}
__device__ __forceinline__ float b2f(u16 u) {
    union { unsigned int i; float f; } c;
    c.i = ((unsigned int)u) << 16;
    return c.f;
}

#define GLDS16(src, dst) __builtin_amdgcn_global_load_lds( \
    (const __attribute__((address_space(1))) void*)(src),  \
    (__attribute__((address_space(3))) void*)(dst), 16, 0, 0)

// ---------------- conversion kernels ----------------

__global__ void convx_kernel(const float* __restrict__ x,
                             u16* __restrict__ xhi, u16* __restrict__ xlo) {
    size_t i = (size_t)(blockIdx.x * 256 + threadIdx.x) * 8;
    float4 v0 = *(const float4*)(x + i);
    float4 v1 = *(const float4*)(x + i + 4);
    float v[8] = {v0.x, v0.y, v0.z, v0.w, v1.x, v1.y, v1.z, v1.w};
    bf16x8 rh, rl;
#pragma unroll
    for (int j = 0; j < 8; ++j) {
        u16 h = f2b(v[j]);
        rh[j] = (short)h;
        rl[j] = (short)f2b(v[j] - b2f(h));
    }
    *(bf16x8*)(xhi + i) = rh;
    *(bf16x8*)(xlo + i) = rl;
}

__global__ void convw_kernel(const float* __restrict__ w1l, const float* __restrict__ w2l,
                             const float* __restrict__ w3l, const float* __restrict__ w1r,
                             const float* __restrict__ w2r,
                             u16* __restrict__ W1LThi, u16* __restrict__ W1LTlo,
                             u16* __restrict__ W1RT,
                             u16* __restrict__ W2LThi, u16* __restrict__ W2LTlo,
                             u16* __restrict__ W2RT,
                             u16* __restrict__ W3LThi, u16* __restrict__ W3LTlo) {
    int i = blockIdx.x * 256 + threadIdx.x;
    if (i < 131072) {                       // w1_lat [256,512] -> [512][256] hi/lo
        int n = i >> 8, k = i & 255;
        float v = w1l[k * 512 + n];
        u16 h = f2b(v);
        W1LThi[i] = h;
        W1LTlo[i] = f2b(v - b2f(h));
    } else if (i < 262144) {                // w1_ro -> [512][256] bf16
        int j = i - 131072;
        int n = j >> 8, k = j & 255;
        W1RT[j] = f2b(w1r[k * 512 + n]);
    } else if (i < 524288) {                // w2_lat [512,512] -> hi/lo
        int j = i - 262144;
        int n = j >> 9, k = j & 511;
        float v = w2l[k * 512 + n];
        u16 h = f2b(v);
        W2LThi[j] = h;
        W2LTlo[j] = f2b(v - b2f(h));
    } else if (i < 786432) {                // w2_ro -> bf16
        int j = i - 524288;
        int n = j >> 9, k = j & 511;
        W2RT[j] = f2b(w2r[k * 512 + n]);
    } else if (i < 851968) {                // w3_lat [512,128] -> [128][512] hi/lo
        int j = i - 786432;
        int n = j >> 9, k = j & 511;
        float v = w3l[k * 128 + n];
        u16 h = f2b(v);
        W3LThi[j] = h;
        W3LTlo[j] = f2b(v - b2f(h));
    }
}

// ---------------- 3-buffer ring MFMA GEMM (counted vmcnt, no drain) ----------------
// C = act( scale * sum_seg Aseg @ Bseg^T ).  BM=256, BN=NF*64, BK=32,
// 512 threads = 8 waves (2M x 4N), per-wave 128 x NF*16 output (acc[8][NF]).
// LDS: 3 buffers (96KB @NF=4) -> 2 tiles of lookahead.  Ring schedule per tile t:
//   [barrier-entered: tile t ready]  stage(t+2) -> ds_read frags(t) ->
//   lgkmcnt(0)+sched_barrier -> setprio{8*NF MFMA} -> vmcnt(LPT) (t+1 landed,
//   t+2 in flight) -> barrier.   No vmcnt(0) drain in the loop (T3+T4).
// Swizzle: 64B LDS rows, source chunk cs = scp ^ ((row>>1)&3), read chunk
// kc ^ ((rlane>>1)&3)  -> 2-way bank alias (free).  Bijective XCD swizzle (T1).
// NSEG=3: K-segments (Ahi,Bhi),(Alo,Bhi),(Ahi,Blo) = split-bf16 ~f32 precision.
// OUTK: 0 = f32, 1 = bf16, 2 = split hi/lo bf16.
template<int NSEG, int GX, int NF, bool SILU, int OUTK>
__global__ void __launch_bounds__(512, 2) gemm_r3(
        const u16* __restrict__ Ahi, const u16* __restrict__ Alo,
        const u16* __restrict__ Bhi, const u16* __restrict__ Blo,
        void* __restrict__ Chi, void* __restrict__ Clo,
        int ldc, int K, float scale) {
    __shared__ __align__(16) u16 lA[3][256 * 32];
    __shared__ __align__(16) u16 lB[3][NF * 64 * 32];
    constexpr int LPT = 2 + NF / 2;     // gload_lds instrs per thread per tile
    const int tid = threadIdx.x;
    const int lane = tid & 63;
    const int wid = tid >> 6;
    const int wm = wid >> 2;            // 0..1 -> 128-row half
    const int wn = wid & 3;             // 0..3 -> NF*16-col quarter
    const int rlane = lane & 15;
    const int kc = lane >> 4;           // 0..3
    const int chp = (kc ^ ((rlane >> 1) & 3)) * 8;   // read chunk offset (u16)
    const int srow = tid >> 2;          // 0..127
    const int scp = tid & 3;            // 0..3
    const int cs = scp ^ ((srow >> 1) & 3);          // swizzled source chunk

    // bijective XCD swizzle (grid % 8 == 0)
    const int nwg = gridDim.x;
    const int bid = blockIdx.x;
    const int wg = (bid & 7) * (nwg >> 3) + (bid >> 3);
    const int bn = (wg % GX) * (NF * 64);
    const int bm = (wg / GX) * 256;

    const int kt = K >> 5;
    const int NT = NSEG * kt;

    auto stage = [&](int t, int b) {
        int seg = (NSEG == 1) ? 0 : ((t >= kt) + (t >= 2 * kt));
        const u16* As = (NSEG == 1) ? Ahi : (seg == 1 ? Alo : Ahi);
        const u16* Bs = (NSEG == 1) ? Bhi : (seg == 2 ? Blo : Bhi);
        int k0 = (t - seg * kt) << 5;
        u16* la = lA[b];
        u16* lb = lB[b];
#pragma unroll
        for (int c = 0; c < 2; ++c) {
            int row = c * 128 + srow;
            GLDS16(As + (size_t)(bm + row) * K + k0 + cs * 8, la + row * 32 + scp * 8);
        }
#pragma unroll
        for (int c = 0; c < NF / 2; ++c) {
            int row = c * 128 + srow;
            GLDS16(Bs + (size_t)(bn + row) * K + k0 + cs * 8, lb + row * 32 + scp * 8);
        }
    };

    f32x4 acc[8][NF] = {};

    // prologue: tiles 0,1 in flight; wait tile 0 only
    stage(0, 0);
    stage(1, 1);
    if constexpr (LPT == 4) asm volatile("s_waitcnt vmcnt(4)" ::: "memory");
    else                    asm volatile("s_waitcnt vmcnt(3)" ::: "memory");
    __builtin_amdgcn_s_barrier();

    int cur = 0;
    for (int t = 0; t < NT; ++t) {
        if (t + 2 < NT) stage(t + 2, cur == 0 ? 2 : cur - 1);   // (cur+2)%3
        const u16* la = lA[cur];
        const u16* lb = lB[cur];
        bf16x8 af[8], bf[NF];
#pragma unroll
        for (int m = 0; m < 8; ++m) {
            int row = wm * 128 + m * 16 + rlane;
            af[m] = *(const bf16x8*)&la[row * 32 + chp];
        }
#pragma unroll
        for (int n = 0; n < NF; ++n) {
            int row = wn * (NF * 16) + n * 16 + rlane;
            bf[n] = *(const bf16x8*)&lb[row * 32 + chp];
        }
        asm volatile("s_waitcnt lgkmcnt(0)" ::: "memory");
        __builtin_amdgcn_sched_barrier(0);
        __builtin_amdgcn_s_setprio(1);
#pragma unroll
        for (int m = 0; m < 8; ++m)
#pragma unroll
            for (int n = 0; n < NF; ++n)
                acc[m][n] = __builtin_amdgcn_mfma_f32_16x16x32_bf16(af[m], bf[n], acc[m][n], 0, 0, 0);
        __builtin_amdgcn_s_setprio(0);
        if (t + 2 < NT) {
            if constexpr (LPT == 4) asm volatile("s_waitcnt vmcnt(4)" ::: "memory");
            else                    asm volatile("s_waitcnt vmcnt(3)" ::: "memory");
        } else {
            asm volatile("s_waitcnt vmcnt(0)" ::: "memory");
        }
        __builtin_amdgcn_s_barrier();
        cur = (cur == 2) ? 0 : cur + 1;
    }

    // epilogue: C/D layout col = lane&15, row = (lane>>4)*4 + reg
#pragma unroll
    for (int m = 0; m < 8; ++m) {
        int grow0 = bm + wm * 128 + m * 16 + ((lane >> 4) << 2);
#pragma unroll
        for (int n = 0; n < NF; ++n) {
            int gcol = bn + wn * (NF * 16) + n * 16 + rlane;
#pragma unroll
            for (int r = 0; r < 4; ++r) {
                float v = acc[m][n][r] * scale;
                if constexpr (SILU) v = v / (1.0f + __expf(-v));
                size_t idx = (size_t)(grow0 + r) * ldc + gcol;
                if constexpr (OUTK == 0) {
                    ((float*)Chi)[idx] = v;
                } else if constexpr (OUTK == 1) {
                    ((u16*)Chi)[idx] = f2b(v);
                } else {
                    u16 h = f2b(v);
                    ((u16*)Chi)[idx] = h;
                    ((u16*)Clo)[idx] = f2b(v - b2f(h));
                }
            }
        }
    }
}

// ---------------- inv_out: H2R [32768,512] bf16 @ w3_ro [512,2] f32 ----------------
__global__ void invout_kernel(const u16* __restrict__ H2b,
                              const float* __restrict__ w3,
                              float* __restrict__ out) {
    int g = blockIdx.x * 256 + threadIdx.x;
    int n = g >> 6;
    int lane = g & 63;
    bf16x8 hv = *(const bf16x8*)(H2b + (size_t)n * 512 + lane * 8);
    float s0 = 0.f, s1 = 0.f;
#pragma unroll
    for (int j = 0; j < 8; ++j) {
        float hf = b2f((u16)hv[j]);
        int k = lane * 8 + j;
        s0 = fmaf(hf, w3[2 * k], s0);
        s1 = fmaf(hf, w3[2 * k + 1], s1);
    }
#pragma unroll
    for (int off = 32; off > 0; off >>= 1) {
        s0 += __shfl_xor(s0, off);
        s1 += __shfl_xor(s1, off);
    }
    if (lane == 0) {
        const float s = 0.04419417382415922f;   // 1/sqrt(512)
        out[2 * n] = s0 * s;
        out[2 * n + 1] = s1 * s;
    }
}

// ---------------- per-atom equivariant output ----------------
__global__ void eq_kernel(const float* __restrict__ eqf, const float* __restrict__ wgt,
                          const int* __restrict__ types, const float* __restrict__ bond,
                          float* __restrict__ out) {
    int t = blockIdx.x * 256 + threadIdx.x;   // 131072 = 32768*4
    int n = t >> 2, v = t & 3;
    const float* e = eqf + (size_t)n * 96;
    const float* w = wgt + (size_t)n * 128 + v;
    float a0 = 0.f, a1 = 0.f, a2 = 0.f;
#pragma unroll
    for (int u = 0; u < 32; ++u) {
        float wv = w[u * 4];
        a0 = fmaf(e[u * 3 + 0], wv, a0);
        a1 = fmaf(e[u * 3 + 1], wv, a1);
        a2 = fmaf(e[u * 3 + 2], wv, a2);
    }
    const float s = 0.17677669529663687f;   // 1/sqrt(32)
    a0 *= s; a1 *= s; a2 *= s;
    float norm = sqrtf(a0 * a0 + a1 * a1 + a2 * a2) + 1e-10f;
    float bl = bond[types[n] * 4 + v];
    float r0 = a0 / norm, r1 = a1 / norm, r2 = a2 / norm;
    if (isnan(r0)) r0 = 0.f;
    if (isnan(r1)) r1 = 0.f;
    if (isnan(r2)) r2 = 0.f;
    out[(size_t)n * 12 + v * 3 + 0] = r0 * bl;
    out[(size_t)n * 12 + v * 3 + 1] = r1 * bl;
    out[(size_t)n * 12 + v * 3 + 2] = r2 * bl;
}

// ---------------- launcher ----------------
extern "C" void kernel_launch(void* const* d_in, const int* in_sizes, int n_in,
                              void* d_out, int out_size, void* d_ws, size_t ws_size,
                              hipStream_t stream) {
    const float* inv  = (const float*)d_in[0];
    const float* eqf  = (const float*)d_in[1];
    const int*   typs = (const int*)d_in[2];
    const float* w1l  = (const float*)d_in[3];
    const float* w2l  = (const float*)d_in[4];
    const float* w3l  = (const float*)d_in[5];
    const float* w1r  = (const float*)d_in[6];
    const float* w2r  = (const float*)d_in[7];
    const float* w3r  = (const float*)d_in[8];
    const float* bond = (const float*)d_in[9];

    char* ws = (char*)d_ws;
    const size_t MB = 1024 * 1024, KB = 1024;
    // live-range-aliased memory map:
    u16* XHI   = (u16*)(ws);            // 16MB [32768][256]
    u16* XLO   = (u16*)(ws + 16 * MB);  // 16MB
    u16* H1R   = (u16*)(ws + 32 * MB);  // 32MB [32768][512]
    u16* H1Lhi = (u16*)(ws + 64 * MB);  // 32MB
    u16* H1Llo = (u16*)(ws + 96 * MB);  // 32MB
    u16* H2R   = (u16*)(ws + 128 * MB); // 32MB
    u16* H2Lhi = (u16*)(ws);            // 32MB, aliases XHI+XLO (dead after ro L1)
    u16* H2Llo = (u16*)(ws + 32 * MB);  // 32MB, aliases H1R (dead after ro L2)
    float* WGT = (float*)(ws + 64 * MB);// 16MB, aliases H1Lhi (dead after lat L2)
    char* wb = ws + 160 * MB;
    u16* W1LThi = (u16*)(wb);               // 256KB [512][256]
    u16* W1LTlo = (u16*)(wb + 256 * KB);    // 256KB
    u16* W1RT   = (u16*)(wb + 512 * KB);    // 256KB
    u16* W2LThi = (u16*)(wb + 768 * KB);    // 512KB [512][512]
    u16* W2LTlo = (u16*)(wb + 1280 * KB);   // 512KB
    u16* W2RT   = (u16*)(wb + 1792 * KB);   // 512KB
    u16* W3LThi = (u16*)(wb + 2304 * KB);   // 128KB [128][512]
    u16* W3LTlo = (u16*)(wb + 2432 * KB);   // 128KB

    float* out_inv = (float*)d_out;                 // [32768][2]
    float* out_eq  = (float*)d_out + N_ATOMS * 2;   // [32768][4][3]

    const float s256 = 0.0625f;                 // 1/sqrt(256)
    const float s512 = 0.04419417382415922f;    // 1/sqrt(512)

    convx_kernel<<<dim3(4096), dim3(256), 0, stream>>>(inv, XHI, XLO);
    convw_kernel<<<dim3(3328), dim3(256), 0, stream>>>(w1l, w2l, w3l, w1r, w2r,
        W1LThi, W1LTlo, W1RT, W2LThi, W2LTlo, W2RT, W3LThi, W3LTlo);

    // lat L1 (split): [32768,256] -> H1L hi/lo (silu)   NT=24
    gemm_r3<3, 2, 4, true, 2><<<dim3(256), dim3(512), 0, stream>>>(
        XHI, XLO, W1LThi, W1LTlo, H1Lhi, H1Llo, 512, 256, s256);
    // ro L1 (bf16): -> H1R (silu)   NT=8
    gemm_r3<1, 2, 4, true, 1><<<dim3(256), dim3(512), 0, stream>>>(
        XHI, nullptr, W1RT, nullptr, H1R, nullptr, 512, 256, s256);
    // ro L2 (bf16): -> H2R (silu)   NT=16  [must precede lat L2: H2Llo aliases H1R]
    gemm_r3<1, 2, 4, true, 1><<<dim3(256), dim3(512), 0, stream>>>(
        H1R, nullptr, W2RT, nullptr, H2R, nullptr, 512, 512, s512);
    // lat L2 (split): -> H2L hi/lo (silu)   NT=48
    gemm_r3<3, 2, 4, true, 2><<<dim3(256), dim3(512), 0, stream>>>(
        H1Lhi, H1Llo, W2LThi, W2LTlo, H2Lhi, H2Llo, 512, 512, s512);
    // lat L3 (split): [32768,512] @ [512,128] -> WGT f32   BN=128, grid 128, NT=48
    gemm_r3<3, 1, 2, false, 0><<<dim3(128), dim3(512), 0, stream>>>(
        H2Lhi, H2Llo, W3LThi, W3LTlo, WGT, nullptr, 128, 512, s512);
    // ro L3
    invout_kernel<<<dim3(8192), dim3(256), 0, stream>>>(H2R, w3r, out_inv);
    // equivariant epilogue
    eq_kernel<<<dim3(512), dim3(256), 0, stream>>>(eqf, WGT, typs, bond, out_eq);
}

// Round 7
// 202.598 us; speedup vs baseline: 1.2415x; 1.2415x over previous
//
#include <hip/hip_runtime.h>
#include <hip/hip_bf16.h>

#define N_ATOMS 32768

typedef __attribute__((ext_vector_type(4))) float f32x4;
typedef __attribute__((ext_vector_type(8))) short bf16x8;
typedef unsigned short u16;

__device__ __forceinline__ u16 f2b(float f) {
    union { __hip_bfloat16 b; u16 u; } c;
    c.b = __float2bfloat16(f);
    return c.u;
}
__device__ __forceinline__ float b2f(u16 u) {
    union { unsigned int i; float f; } c;
    c.i = ((unsigned int)u) << 16;
    return c.f;
}

#define GLDS16(src, dst) __builtin_amdgcn_global_load_lds( \
    (const __attribute__((address_space(1))) void*)(src),  \
    (__attribute__((address_space(3))) void*)(dst), 16, 0, 0)

// ---------------- conversion kernels ----------------

__global__ void convx_kernel(const float* __restrict__ x,
                             u16* __restrict__ xhi, u16* __restrict__ xlo) {
    size_t i = (size_t)(blockIdx.x * 256 + threadIdx.x) * 8;
    float4 v0 = *(const float4*)(x + i);
    float4 v1 = *(const float4*)(x + i + 4);
    float v[8] = {v0.x, v0.y, v0.z, v0.w, v1.x, v1.y, v1.z, v1.w};
    bf16x8 rh, rl;
#pragma unroll
    for (int j = 0; j < 8; ++j) {
        u16 h = f2b(v[j]);
        rh[j] = (short)h;
        rl[j] = (short)f2b(v[j] - b2f(h));
    }
    *(bf16x8*)(xhi + i) = rh;
    *(bf16x8*)(xlo + i) = rl;
}

__global__ void convw_kernel(const float* __restrict__ w1l, const float* __restrict__ w2l,
                             const float* __restrict__ w3l, const float* __restrict__ w1r,
                             const float* __restrict__ w2r,
                             u16* __restrict__ W1LThi, u16* __restrict__ W1LTlo,
                             u16* __restrict__ W1RT,
                             u16* __restrict__ W2LThi, u16* __restrict__ W2LTlo,
                             u16* __restrict__ W2RT,
                             u16* __restrict__ W3LThi, u16* __restrict__ W3LTlo) {
    int i = blockIdx.x * 256 + threadIdx.x;
    if (i < 131072) {                       // w1_lat [256,512] -> [512][256] hi/lo
        int n = i >> 8, k = i & 255;
        float v = w1l[k * 512 + n];
        u16 h = f2b(v);
        W1LThi[i] = h;
        W1LTlo[i] = f2b(v - b2f(h));
    } else if (i < 262144) {                // w1_ro -> [512][256] bf16
        int j = i - 131072;
        int n = j >> 8, k = j & 255;
        W1RT[j] = f2b(w1r[k * 512 + n]);
    } else if (i < 524288) {                // w2_lat [512,512] -> hi/lo
        int j = i - 262144;
        int n = j >> 9, k = j & 511;
        float v = w2l[k * 512 + n];
        u16 h = f2b(v);
        W2LThi[j] = h;
        W2LTlo[j] = f2b(v - b2f(h));
    } else if (i < 786432) {                // w2_ro -> bf16
        int j = i - 524288;
        int n = j >> 9, k = j & 511;
        W2RT[j] = f2b(w2r[k * 512 + n]);
    } else if (i < 851968) {                // w3_lat [512,128] -> [128][512] hi/lo
        int j = i - 786432;
        int n = j >> 9, k = j & 511;
        float v = w3l[k * 128 + n];
        u16 h = f2b(v);
        W3LThi[j] = h;
        W3LTlo[j] = f2b(v - b2f(h));
    }
}

// ---------------- zero out_inv (d_out not re-poisoned between replays) ----------------
__global__ void zero_kernel(float* __restrict__ p) {
    int i = blockIdx.x * 256 + threadIdx.x;   // 16384 threads x 4 floats = 65536
    *(float4*)(p + i * 4) = float4{0.f, 0.f, 0.f, 0.f};
}

// ---------------- 256-row 8-wave MFMA GEMM (R4-proven schedule) ----------------
// C = act( scale * sum_seg Aseg @ Bseg^T ).  BM=256, BN=NF*64, BK=64,
// 512 threads = 8 waves (2M x 4N), per-wave 128 x NF*16 output (acc[8][NF]).
// Per K-tile: 2 phases {ds_read frags | stage half of next tile | lgkmcnt(0)
// | setprio(1) MFMA setprio(0)}, then vmcnt(0)+barrier.
// NSEG=3: K-segments (Ahi,Bhi),(Alo,Bhi),(Ahi,Blo) = split-bf16 ~f32 precision.
// OUTK: 0 = f32, 1 = bf16, 2 = split hi/lo bf16,
//       3 = fused invout (dot w3_ro -> atomicAdd e_out, nothing else stored),
//       4 = fused eq epilogue (stage WGT block to LDS, einsum/norm/bond -> e_out).
template<int NSEG, int GX, int NF, bool SILU, int OUTK>
__global__ void __launch_bounds__(512, 2) gemm8p(
        const u16* __restrict__ Ahi, const u16* __restrict__ Alo,
        const u16* __restrict__ Bhi, const u16* __restrict__ Blo,
        void* __restrict__ Chi, void* __restrict__ Clo,
        int ldc, int K, float scale,
        const float* __restrict__ e_w3, const float* __restrict__ e_eqf,
        const int* __restrict__ e_types, const float* __restrict__ e_bond,
        float* __restrict__ e_out) {
    constexpr int SMEMN = (NF == 4 || OUTK == 4) ? 65536 : 49152;
    constexpr int LBSZ = NF * 64 * 64;      // u16 per B buffer
    __shared__ __align__(16) u16 smem[SMEMN];
    u16* const lA0 = smem;                  // 2 x 16384
    u16* const lB0 = smem + 32768;          // 2 x LBSZ
    const int tid = threadIdx.x;
    const int lane = tid & 63;
    const int wid = tid >> 6;
    const int wm = wid >> 2;            // 0..1 -> 128-row half
    const int wn = wid & 3;             // 0..3 -> NF*16-col quarter
    const int rlane = lane & 15;
    const int kc = lane >> 4;           // 0..3
    const int cps = rlane & 7;
    const int srow = tid >> 3;          // 0..63
    const int scp = tid & 7;

    // bijective XCD swizzle (grid % 8 == 0)
    const int nwg = gridDim.x;
    const int bid = blockIdx.x;
    const int wg = (bid & 7) * (nwg >> 3) + (bid >> 3);
    const int bn = (wg % GX) * (NF * 64);
    const int bm = (wg / GX) * 256;

    const int kt = K >> 6;
    const int NT = NSEG * kt;

    auto stageA = [&](int t, int buf) {
        int seg = (NSEG == 1) ? 0 : ((t >= kt) + (t >= 2 * kt));
        const u16* As = (NSEG == 1) ? Ahi : (seg == 1 ? Alo : Ahi);
        int k0 = (t - seg * kt) << 6;
        u16* la = lA0 + buf * 16384;
#pragma unroll
        for (int call = 0; call < 4; ++call) {
            int row = call * 64 + srow;
            int c = scp ^ (row & 7);    // pre-swizzled global source, linear LDS dest
            GLDS16(As + (size_t)(bm + row) * K + k0 + c * 8, la + (size_t)(row * 64 + scp * 8));
        }
    };
    auto stageB = [&](int t, int buf) {
        int seg = (NSEG == 1) ? 0 : ((t >= kt) + (t >= 2 * kt));
        const u16* Bs = (NSEG == 1) ? Bhi : (seg == 2 ? Blo : Bhi);
        int k0 = (t - seg * kt) << 6;
        u16* lb = lB0 + buf * LBSZ;
#pragma unroll
        for (int call = 0; call < NF; ++call) {
            int row = call * 64 + srow;
            int c = scp ^ (row & 7);
            GLDS16(Bs + (size_t)(bn + row) * K + k0 + c * 8, lb + (size_t)(row * 64 + scp * 8));
        }
    };

    f32x4 acc[8][NF] = {};

    // prologue: tile 0 in flight, then sync
    stageA(0, 0);
    stageB(0, 0);
    asm volatile("s_waitcnt vmcnt(0)" ::: "memory");
    __builtin_amdgcn_s_barrier();

    for (int t = 0; t < NT; ++t) {
        const int cur = t & 1, nxt = cur ^ 1;
        const bool pf = (t + 1 < NT);
        const u16* la = lA0 + cur * 16384;
        const u16* lb = lB0 + cur * LBSZ;
#pragma unroll
        for (int ks = 0; ks < 2; ++ks) {
            bf16x8 af[8], bfr[NF];
            const int cp = (ks * 4 + kc) ^ cps;
#pragma unroll
            for (int m = 0; m < 8; ++m) {
                int row = wm * 128 + m * 16 + rlane;
                af[m] = *(const bf16x8*)&la[row * 64 + cp * 8];
            }
#pragma unroll
            for (int n = 0; n < NF; ++n) {
                int row = wn * (NF * 16) + n * 16 + rlane;
                bfr[n] = *(const bf16x8*)&lb[row * 64 + cp * 8];
            }
            if (pf) {                       // issue next tile's loads early (stay in flight)
                if (ks == 0) stageA(t + 1, nxt);
                else         stageB(t + 1, nxt);
            }
            asm volatile("s_waitcnt lgkmcnt(0)" ::: "memory");
            __builtin_amdgcn_sched_barrier(0);
            __builtin_amdgcn_s_setprio(1);
#pragma unroll
            for (int m = 0; m < 8; ++m)
#pragma unroll
                for (int n = 0; n < NF; ++n)
                    acc[m][n] = __builtin_amdgcn_mfma_f32_16x16x32_bf16(af[m], bfr[n], acc[m][n], 0, 0, 0);
            __builtin_amdgcn_s_setprio(0);
        }
        asm volatile("s_waitcnt vmcnt(0)" ::: "memory");   // next tile's loads landed
        __builtin_amdgcn_s_barrier();                      // all waves done reading cur
    }

    const int g = lane >> 4;

    if constexpr (OUTK == 3) {
        // fused invout: out[row,j] += sum_col silu(acc*scale) * w3[col,j] / sqrt(512)
        const float s512f = 0.04419417382415922f;
        float wj0[NF], wj1[NF];
#pragma unroll
        for (int n = 0; n < NF; ++n) {
            int gc = bn + wn * (NF * 16) + n * 16 + rlane;
            wj0[n] = e_w3[gc * 2] * s512f;
            wj1[n] = e_w3[gc * 2 + 1] * s512f;
        }
#pragma unroll
        for (int m = 0; m < 8; ++m)
#pragma unroll
            for (int r = 0; r < 4; ++r) {
                float s0 = 0.f, s1 = 0.f;
#pragma unroll
                for (int n = 0; n < NF; ++n) {
                    float v = acc[m][n][r] * scale;
                    v = v / (1.0f + __expf(-v));
                    s0 = fmaf(v, wj0[n], s0);
                    s1 = fmaf(v, wj1[n], s1);
                }
#pragma unroll
                for (int off = 1; off < 16; off <<= 1) {
                    s0 += __shfl_xor(s0, off);
                    s1 += __shfl_xor(s1, off);
                }
                if (rlane == 0) {
                    int row = bm + wm * 128 + m * 16 + g * 4 + r;
                    atomicAdd(&e_out[row * 2], s0);
                    atomicAdd(&e_out[row * 2 + 1], s1);
                }
            }
        return;
    } else if constexpr (OUTK == 4) {
        // fused eq epilogue: stage WGT block [256][128] f32 into LDS (swizzled)
        float* wgt = (float*)smem;
#pragma unroll
        for (int m = 0; m < 8; ++m)
#pragma unroll
            for (int n = 0; n < NF; ++n)
#pragma unroll
                for (int r = 0; r < 4; ++r) {
                    int rl_ = wm * 128 + m * 16 + g * 4 + r;
                    int cl_ = wn * (NF * 16) + n * 16 + rlane;
                    wgt[rl_ * 128 + ((cl_ + rl_) & 127)] = acc[m][n][r] * scale;
                }
        __syncthreads();
        // eq: 2 threads per atom, each handles 2 of 4 v's
        int nl = tid >> 1;
        int na = bm + nl;
        int vb = (tid & 1) * 2;
        const float* e = e_eqf + (size_t)na * 96;
        int ty = e_types[na];
        const float s32 = 0.17677669529663687f;   // 1/sqrt(32)
#pragma unroll
        for (int v = vb; v < vb + 2; ++v) {
            float a0 = 0.f, a1 = 0.f, a2 = 0.f;
#pragma unroll
            for (int u = 0; u < 32; ++u) {
                float wv = wgt[nl * 128 + ((4 * u + v + nl) & 127)];
                a0 = fmaf(e[u * 3 + 0], wv, a0);
                a1 = fmaf(e[u * 3 + 1], wv, a1);
                a2 = fmaf(e[u * 3 + 2], wv, a2);
            }
            a0 *= s32; a1 *= s32; a2 *= s32;
            float nrm = sqrtf(a0 * a0 + a1 * a1 + a2 * a2) + 1e-10f;
            float bl = e_bond[ty * 4 + v];
            float r0 = a0 / nrm, r1 = a1 / nrm, r2 = a2 / nrm;
            if (isnan(r0)) r0 = 0.f;
            if (isnan(r1)) r1 = 0.f;
            if (isnan(r2)) r2 = 0.f;
            e_out[(size_t)na * 12 + v * 3 + 0] = r0 * bl;
            e_out[(size_t)na * 12 + v * 3 + 1] = r1 * bl;
            e_out[(size_t)na * 12 + v * 3 + 2] = r2 * bl;
        }
        return;
    } else {
        // standard epilogue: C/D layout col = lane&15, row = (lane>>4)*4 + reg
#pragma unroll
        for (int m = 0; m < 8; ++m) {
            int grow0 = bm + wm * 128 + m * 16 + (g << 2);
#pragma unroll
            for (int n = 0; n < NF; ++n) {
                int gcol = bn + wn * (NF * 16) + n * 16 + rlane;
#pragma unroll
                for (int r = 0; r < 4; ++r) {
                    float v = acc[m][n][r] * scale;
                    if constexpr (SILU) v = v / (1.0f + __expf(-v));
                    size_t idx = (size_t)(grow0 + r) * ldc + gcol;
                    if constexpr (OUTK == 0) {
                        ((float*)Chi)[idx] = v;
                    } else if constexpr (OUTK == 1) {
                        ((u16*)Chi)[idx] = f2b(v);
                    } else {
                        u16 h = f2b(v);
                        ((u16*)Chi)[idx] = h;
                        ((u16*)Clo)[idx] = f2b(v - b2f(h));
                    }
                }
            }
        }
    }
}

// ---------------- launcher ----------------
extern "C" void kernel_launch(void* const* d_in, const int* in_sizes, int n_in,
                              void* d_out, int out_size, void* d_ws, size_t ws_size,
                              hipStream_t stream) {
    const float* inv  = (const float*)d_in[0];
    const float* eqf  = (const float*)d_in[1];
    const int*   typs = (const int*)d_in[2];
    const float* w1l  = (const float*)d_in[3];
    const float* w2l  = (const float*)d_in[4];
    const float* w3l  = (const float*)d_in[5];
    const float* w1r  = (const float*)d_in[6];
    const float* w2r  = (const float*)d_in[7];
    const float* w3r  = (const float*)d_in[8];
    const float* bond = (const float*)d_in[9];

    char* ws = (char*)d_ws;
    const size_t MB = 1024 * 1024, KB = 1024;
    // live-range-aliased memory map (163MB, same budget as proven rounds):
    u16* XHI   = (u16*)(ws);            // 16MB [32768][256]
    u16* XLO   = (u16*)(ws + 16 * MB);  // 16MB
    u16* H1R   = (u16*)(ws + 32 * MB);  // 32MB [32768][512]
    u16* H1Lhi = (u16*)(ws + 64 * MB);  // 32MB
    u16* H1Llo = (u16*)(ws + 96 * MB);  // 32MB
    u16* H2Lhi = (u16*)(ws);            // 32MB, aliases XHI+XLO (dead after both L1s)
    u16* H2Llo = (u16*)(ws + 32 * MB);  // 32MB, aliases H1R (dead after fused ro-L2)
    char* wb = ws + 160 * MB;
    u16* W1LThi = (u16*)(wb);               // 256KB [512][256]
    u16* W1LTlo = (u16*)(wb + 256 * KB);    // 256KB
    u16* W1RT   = (u16*)(wb + 512 * KB);    // 256KB
    u16* W2LThi = (u16*)(wb + 768 * KB);    // 512KB [512][512]
    u16* W2LTlo = (u16*)(wb + 1280 * KB);   // 512KB
    u16* W2RT   = (u16*)(wb + 1792 * KB);   // 512KB
    u16* W3LThi = (u16*)(wb + 2304 * KB);   // 128KB [128][512]
    u16* W3LTlo = (u16*)(wb + 2432 * KB);   // 128KB

    float* out_inv = (float*)d_out;                 // [32768][2]
    float* out_eq  = (float*)d_out + N_ATOMS * 2;   // [32768][4][3]

    const float s256 = 0.0625f;                 // 1/sqrt(256)
    const float s512 = 0.04419417382415922f;    // 1/sqrt(512)

    convx_kernel<<<dim3(4096), dim3(256), 0, stream>>>(inv, XHI, XLO);
    convw_kernel<<<dim3(3328), dim3(256), 0, stream>>>(w1l, w2l, w3l, w1r, w2r,
        W1LThi, W1LTlo, W1RT, W2LThi, W2LTlo, W2RT, W3LThi, W3LTlo);
    zero_kernel<<<dim3(64), dim3(256), 0, stream>>>(out_inv);

    // lat L1 (split): [32768,256] -> H1L hi/lo (silu)
    gemm8p<3, 2, 4, true, 2><<<dim3(256), dim3(512), 0, stream>>>(
        XHI, XLO, W1LThi, W1LTlo, H1Lhi, H1Llo, 512, 256, s256,
        nullptr, nullptr, nullptr, nullptr, nullptr);
    // ro L1 (bf16): -> H1R (silu)
    gemm8p<1, 2, 4, true, 1><<<dim3(256), dim3(512), 0, stream>>>(
        XHI, nullptr, W1RT, nullptr, H1R, nullptr, 512, 256, s256,
        nullptr, nullptr, nullptr, nullptr, nullptr);
    // ro L2 + invout fused: H2R never materialized; atomics into out_inv
    gemm8p<1, 2, 4, true, 3><<<dim3(256), dim3(512), 0, stream>>>(
        H1R, nullptr, W2RT, nullptr, nullptr, nullptr, 0, 512, s512,
        w3r, nullptr, nullptr, nullptr, out_inv);
    // lat L2 (split): -> H2L hi/lo (silu)   [after fused ro-L2: H2Llo aliases H1R]
    gemm8p<3, 2, 4, true, 2><<<dim3(256), dim3(512), 0, stream>>>(
        H1Lhi, H1Llo, W2LThi, W2LTlo, H2Lhi, H2Llo, 512, 512, s512,
        nullptr, nullptr, nullptr, nullptr, nullptr);
    // lat L3 + eq fused: [32768,512] @ [512,128], WGT staged in LDS, eq epilogue
    gemm8p<3, 1, 2, false, 4><<<dim3(128), dim3(512), 0, stream>>>(
        H2Lhi, H2Llo, W3LThi, W3LTlo, nullptr, nullptr, 0, 512, s512,
        nullptr, eqf, typs, bond, out_eq);
}

// Round 9
// 196.509 us; speedup vs baseline: 1.2800x; 1.0310x over previous
//
#include <hip/hip_runtime.h>
#include <hip/hip_bf16.h>

#define N_ATOMS 32768

typedef __attribute__((ext_vector_type(4))) float f32x4;
typedef __attribute__((ext_vector_type(8))) short bf16x8;
typedef unsigned short u16;

__device__ __forceinline__ u16 f2b(float f) {
    union { __hip_bfloat16 b; u16 u; } c;
    c.b = __float2bfloat16(f);
    return c.u;
}
__device__ __forceinline__ float b2f(u16 u) {
    union { unsigned int i; float f; } c;
    c.i = ((unsigned int)u) << 16;
    return c.f;
}

#define GLDS16(src, dst) __builtin_amdgcn_global_load_lds( \
    (const __attribute__((address_space(1))) void*)(src),  \
    (__attribute__((address_space(3))) void*)(dst), 16, 0, 0)

// ---------------- conversion kernels ----------------

__global__ void convx_kernel(const float* __restrict__ x,
                             u16* __restrict__ xhi, u16* __restrict__ xlo) {
    size_t i = (size_t)(blockIdx.x * 256 + threadIdx.x) * 8;
    float4 v0 = *(const float4*)(x + i);
    float4 v1 = *(const float4*)(x + i + 4);
    float v[8] = {v0.x, v0.y, v0.z, v0.w, v1.x, v1.y, v1.z, v1.w};
    bf16x8 rh, rl;
#pragma unroll
    for (int j = 0; j < 8; ++j) {
        u16 h = f2b(v[j]);
        rh[j] = (short)h;
        rl[j] = (short)f2b(v[j] - b2f(h));
    }
    *(bf16x8*)(xhi + i) = rh;
    *(bf16x8*)(xlo + i) = rl;
}

__global__ void convw_kernel(const float* __restrict__ w1l, const float* __restrict__ w2l,
                             const float* __restrict__ w3l, const float* __restrict__ w1r,
                             const float* __restrict__ w2r,
                             u16* __restrict__ W1LThi, u16* __restrict__ W1LTlo,
                             u16* __restrict__ W1RT,
                             u16* __restrict__ W2LThi, u16* __restrict__ W2LTlo,
                             u16* __restrict__ W2RT,
                             u16* __restrict__ W3LThi, u16* __restrict__ W3LTlo) {
    int i = blockIdx.x * 256 + threadIdx.x;
    if (i < 131072) {                       // w1_lat [256,512] -> [512][256] hi/lo
        int n = i >> 8, k = i & 255;
        float v = w1l[k * 512 + n];
        u16 h = f2b(v);
        W1LThi[i] = h;
        W1LTlo[i] = f2b(v - b2f(h));
    } else if (i < 262144) {                // w1_ro -> [512][256] bf16
        int j = i - 131072;
        int n = j >> 8, k = j & 255;
        W1RT[j] = f2b(w1r[k * 512 + n]);
    } else if (i < 524288) {                // w2_lat [512,512] -> hi/lo
        int j = i - 262144;
        int n = j >> 9, k = j & 511;
        float v = w2l[k * 512 + n];
        u16 h = f2b(v);
        W2LThi[j] = h;
        W2LTlo[j] = f2b(v - b2f(h));
    } else if (i < 786432) {                // w2_ro -> bf16
        int j = i - 524288;
        int n = j >> 9, k = j & 511;
        W2RT[j] = f2b(w2r[k * 512 + n]);
    } else if (i < 851968) {                // w3_lat [512,128] -> [128][512] hi/lo
        int j = i - 786432;
        int n = j >> 9, k = j & 511;
        float v = w3l[k * 128 + n];
        u16 h = f2b(v);
        W3LThi[j] = h;
        W3LTlo[j] = f2b(v - b2f(h));
    }
}

// ---------------- zero out_inv (d_out not re-poisoned between replays) ----------------
__global__ void zero_kernel(float* __restrict__ p) {
    int i = blockIdx.x * 256 + threadIdx.x;   // 16384 threads x 4 floats = 65536
    *(float4*)(p + i * 4) = float4{0.f, 0.f, 0.f, 0.f};
}

// ---------------- 256-row 8-wave MFMA GEMM (R4/R7-proven schedule) ----------------
// C = act( scale * sum_seg Aseg @ Bseg^T ).  BM=256, BN=NF*64, BK=64,
// 512 threads = 8 waves (2M x 4N), per-wave 128 x NF*16 output (acc[8][NF]).
// Per K-tile: 2 phases {ds_read frags | stage half of next tile | lgkmcnt(0)
// | setprio(1) MFMA setprio(0)}, then vmcnt(0)+barrier.
// NSEG=3: K-segments (Ahi,Bhi),(Alo,Bhi),(Ahi,Blo) = split-bf16 ~f32 precision.
// OUTK: 0 = f32, 1 = bf16, 2 = split hi/lo bf16,
//       3 = fused invout (dot w3_ro -> atomicAdd e_out, nothing else stored).
template<int NSEG, int GX, int NF, bool SILU, int OUTK>
__global__ void __launch_bounds__(512, 2) gemm8p(
        const u16* __restrict__ Ahi, const u16* __restrict__ Alo,
        const u16* __restrict__ Bhi, const u16* __restrict__ Blo,
        void* __restrict__ Chi, void* __restrict__ Clo,
        int ldc, int K, float scale,
        const float* __restrict__ e_w3, float* __restrict__ e_out) {
    constexpr int LBSZ = NF * 64 * 64;      // u16 per B buffer
    constexpr int SMEMN = 32768 + 2 * LBSZ; // 2 A buffers + 2 B buffers
    __shared__ __align__(16) u16 smem[SMEMN];
    u16* const lA0 = smem;                  // 2 x 16384
    u16* const lB0 = smem + 32768;          // 2 x LBSZ
    const int tid = threadIdx.x;
    const int lane = tid & 63;
    const int wid = tid >> 6;
    const int wm = wid >> 2;            // 0..1 -> 128-row half
    const int wn = wid & 3;             // 0..3 -> NF*16-col quarter
    const int rlane = lane & 15;
    const int kc = lane >> 4;           // 0..3
    const int cps = rlane & 7;
    const int srow = tid >> 3;          // 0..63
    const int scp = tid & 7;

    // bijective XCD swizzle (grid % 8 == 0)
    const int nwg = gridDim.x;
    const int bid = blockIdx.x;
    const int wg = (bid & 7) * (nwg >> 3) + (bid >> 3);
    const int bn = (wg % GX) * (NF * 64);
    const int bm = (wg / GX) * 256;

    const int kt = K >> 6;
    const int NT = NSEG * kt;

    auto stageA = [&](int t, int buf) {
        int seg = (NSEG == 1) ? 0 : ((t >= kt) + (t >= 2 * kt));
        const u16* As = (NSEG == 1) ? Ahi : (seg == 1 ? Alo : Ahi);
        int k0 = (t - seg * kt) << 6;
        u16* la = lA0 + buf * 16384;
#pragma unroll
        for (int call = 0; call < 4; ++call) {
            int row = call * 64 + srow;
            int c = scp ^ (row & 7);    // pre-swizzled global source, linear LDS dest
            GLDS16(As + (size_t)(bm + row) * K + k0 + c * 8, la + (size_t)(row * 64 + scp * 8));
        }
    };
    auto stageB = [&](int t, int buf) {
        int seg = (NSEG == 1) ? 0 : ((t >= kt) + (t >= 2 * kt));
        const u16* Bs = (NSEG == 1) ? Bhi : (seg == 2 ? Blo : Bhi);
        int k0 = (t - seg * kt) << 6;
        u16* lb = lB0 + buf * LBSZ;
#pragma unroll
        for (int call = 0; call < NF; ++call) {
            int row = call * 64 + srow;
            int c = scp ^ (row & 7);
            GLDS16(Bs + (size_t)(bn + row) * K + k0 + c * 8, lb + (size_t)(row * 64 + scp * 8));
        }
    };

    f32x4 acc[8][NF] = {};

    // prologue: tile 0 in flight, then sync
    stageA(0, 0);
    stageB(0, 0);
    asm volatile("s_waitcnt vmcnt(0)" ::: "memory");
    __builtin_amdgcn_s_barrier();

    for (int t = 0; t < NT; ++t) {
        const int cur = t & 1, nxt = cur ^ 1;
        const bool pf = (t + 1 < NT);
        const u16* la = lA0 + cur * 16384;
        const u16* lb = lB0 + cur * LBSZ;
#pragma unroll
        for (int ks = 0; ks < 2; ++ks) {
            bf16x8 af[8], bfr[NF];
            const int cp = (ks * 4 + kc) ^ cps;
#pragma unroll
            for (int m = 0; m < 8; ++m) {
                int row = wm * 128 + m * 16 + rlane;
                af[m] = *(const bf16x8*)&la[row * 64 + cp * 8];
            }
#pragma unroll
            for (int n = 0; n < NF; ++n) {
                int row = wn * (NF * 16) + n * 16 + rlane;
                bfr[n] = *(const bf16x8*)&lb[row * 64 + cp * 8];
            }
            if (pf) {                       // issue next tile's loads early (stay in flight)
                if (ks == 0) stageA(t + 1, nxt);
                else         stageB(t + 1, nxt);
            }
            asm volatile("s_waitcnt lgkmcnt(0)" ::: "memory");
            __builtin_amdgcn_sched_barrier(0);
            __builtin_amdgcn_s_setprio(1);
#pragma unroll
            for (int m = 0; m < 8; ++m)
#pragma unroll
                for (int n = 0; n < NF; ++n)
                    acc[m][n] = __builtin_amdgcn_mfma_f32_16x16x32_bf16(af[m], bfr[n], acc[m][n], 0, 0, 0);
            __builtin_amdgcn_s_setprio(0);
        }
        asm volatile("s_waitcnt vmcnt(0)" ::: "memory");   // next tile's loads landed
        __builtin_amdgcn_s_barrier();                      // all waves done reading cur
    }

    const int g = lane >> 4;

    if constexpr (OUTK == 3) {
        // fused invout: out[row,j] += sum_col silu(acc*scale) * w3[col,j] / sqrt(512)
        const float s512f = 0.04419417382415922f;
        float wj0[NF], wj1[NF];
#pragma unroll
        for (int n = 0; n < NF; ++n) {
            int gc = bn + wn * (NF * 16) + n * 16 + rlane;
            wj0[n] = e_w3[gc * 2] * s512f;
            wj1[n] = e_w3[gc * 2 + 1] * s512f;
        }
#pragma unroll
        for (int m = 0; m < 8; ++m)
#pragma unroll
            for (int r = 0; r < 4; ++r) {
                float s0 = 0.f, s1 = 0.f;
#pragma unroll
                for (int n = 0; n < NF; ++n) {
                    float v = acc[m][n][r] * scale;
                    v = v / (1.0f + __expf(-v));
                    s0 = fmaf(v, wj0[n], s0);
                    s1 = fmaf(v, wj1[n], s1);
                }
#pragma unroll
                for (int off = 1; off < 16; off <<= 1) {
                    s0 += __shfl_xor(s0, off);
                    s1 += __shfl_xor(s1, off);
                }
                if (rlane == 0) {
                    int row = bm + wm * 128 + m * 16 + g * 4 + r;
                    atomicAdd(&e_out[row * 2], s0);
                    atomicAdd(&e_out[row * 2 + 1], s1);
                }
            }
        return;
    } else {
        // standard epilogue: C/D layout col = lane&15, row = (lane>>4)*4 + reg
#pragma unroll
        for (int m = 0; m < 8; ++m) {
            int grow0 = bm + wm * 128 + m * 16 + (g << 2);
#pragma unroll
            for (int n = 0; n < NF; ++n) {
                int gcol = bn + wn * (NF * 16) + n * 16 + rlane;
#pragma unroll
                for (int r = 0; r < 4; ++r) {
                    float v = acc[m][n][r] * scale;
                    if constexpr (SILU) v = v / (1.0f + __expf(-v));
                    size_t idx = (size_t)(grow0 + r) * ldc + gcol;
                    if constexpr (OUTK == 0) {
                        ((float*)Chi)[idx] = v;
                    } else if constexpr (OUTK == 1) {
                        ((u16*)Chi)[idx] = f2b(v);
                    } else {
                        u16 h = f2b(v);
                        ((u16*)Chi)[idx] = h;
                        ((u16*)Clo)[idx] = f2b(v - b2f(h));
                    }
                }
            }
        }
    }
}

// ---------------- per-atom equivariant output (R2-verified) ----------------
__global__ void eq_kernel(const float* __restrict__ eqf, const float* __restrict__ wgt,
                          const int* __restrict__ types, const float* __restrict__ bond,
                          float* __restrict__ out) {
    int t = blockIdx.x * 256 + threadIdx.x;   // 131072 = 32768*4
    int n = t >> 2, v = t & 3;
    const float* e = eqf + (size_t)n * 96;
    const float* w = wgt + (size_t)n * 128 + v;
    float a0 = 0.f, a1 = 0.f, a2 = 0.f;
#pragma unroll
    for (int u = 0; u < 32; ++u) {
        float wv = w[u * 4];
        a0 = fmaf(e[u * 3 + 0], wv, a0);
        a1 = fmaf(e[u * 3 + 1], wv, a1);
        a2 = fmaf(e[u * 3 + 2], wv, a2);
    }
    const float s = 0.17677669529663687f;   // 1/sqrt(32)
    a0 *= s; a1 *= s; a2 *= s;
    float norm = sqrtf(a0 * a0 + a1 * a1 + a2 * a2) + 1e-10f;
    float bl = bond[types[n] * 4 + v];
    float r0 = a0 / norm, r1 = a1 / norm, r2 = a2 / norm;
    if (isnan(r0)) r0 = 0.f;
    if (isnan(r1)) r1 = 0.f;
    if (isnan(r2)) r2 = 0.f;
    out[(size_t)n * 12 + v * 3 + 0] = r0 * bl;
    out[(size_t)n * 12 + v * 3 + 1] = r1 * bl;
    out[(size_t)n * 12 + v * 3 + 2] = r2 * bl;
}

// ---------------- launcher ----------------
extern "C" void kernel_launch(void* const* d_in, const int* in_sizes, int n_in,
                              void* d_out, int out_size, void* d_ws, size_t ws_size,
                              hipStream_t stream) {
    const float* inv  = (const float*)d_in[0];
    const float* eqf  = (const float*)d_in[1];
    const int*   typs = (const int*)d_in[2];
    const float* w1l  = (const float*)d_in[3];
    const float* w2l  = (const float*)d_in[4];
    const float* w3l  = (const float*)d_in[5];
    const float* w1r  = (const float*)d_in[6];
    const float* w2r  = (const float*)d_in[7];
    const float* w3r  = (const float*)d_in[8];
    const float* bond = (const float*)d_in[9];

    char* ws = (char*)d_ws;
    const size_t MB = 1024 * 1024, KB = 1024;
    // live-range-aliased memory map:
    u16* XHI   = (u16*)(ws);            // 16MB [32768][256]
    u16* XLO   = (u16*)(ws + 16 * MB);  // 16MB
    u16* H1R   = (u16*)(ws + 32 * MB);  // 32MB [32768][512]
    u16* H1Lhi = (u16*)(ws + 64 * MB);  // 32MB
    u16* H1Llo = (u16*)(ws + 96 * MB);  // 32MB
    u16* H2Lhi = (u16*)(ws);            // 32MB, aliases XHI+XLO (dead after both L1s)
    u16* H2Llo = (u16*)(ws + 32 * MB);  // 32MB, aliases H1R (dead after fused ro-L2)
    float* WGT = (float*)(ws + 64 * MB);// 16MB, aliases H1Lhi (dead after lat L2)
    char* wb = ws + 160 * MB;
    u16* W1LThi = (u16*)(wb);               // 256KB [512][256]
    u16* W1LTlo = (u16*)(wb + 256 * KB);    // 256KB
    u16* W1RT   = (u16*)(wb + 512 * KB);    // 256KB
    u16* W2LThi = (u16*)(wb + 768 * KB);    // 512KB [512][512]
    u16* W2LTlo = (u16*)(wb + 1280 * KB);   // 512KB
    u16* W2RT   = (u16*)(wb + 1792 * KB);   // 512KB
    u16* W3LThi = (u16*)(wb + 2304 * KB);   // 128KB [128][512]
    u16* W3LTlo = (u16*)(wb + 2432 * KB);   // 128KB

    float* out_inv = (float*)d_out;                 // [32768][2]
    float* out_eq  = (float*)d_out + N_ATOMS * 2;   // [32768][4][3]

    const float s256 = 0.0625f;                 // 1/sqrt(256)
    const float s512 = 0.04419417382415922f;    // 1/sqrt(512)

    convx_kernel<<<dim3(4096), dim3(256), 0, stream>>>(inv, XHI, XLO);
    convw_kernel<<<dim3(3328), dim3(256), 0, stream>>>(w1l, w2l, w3l, w1r, w2r,
        W1LThi, W1LTlo, W1RT, W2LThi, W2LTlo, W2RT, W3LThi, W3LTlo);
    zero_kernel<<<dim3(64), dim3(256), 0, stream>>>(out_inv);

    // lat L1 (split): [32768,256] -> H1L hi/lo (silu)
    gemm8p<3, 2, 4, true, 2><<<dim3(256), dim3(512), 0, stream>>>(
        XHI, XLO, W1LThi, W1LTlo, H1Lhi, H1Llo, 512, 256, s256, nullptr, nullptr);
    // ro L1 (bf16): -> H1R (silu)
    gemm8p<1, 2, 4, true, 1><<<dim3(256), dim3(512), 0, stream>>>(
        XHI, nullptr, W1RT, nullptr, H1R, nullptr, 512, 256, s256, nullptr, nullptr);
    // ro L2 + invout fused: H2R never materialized; atomics into out_inv
    gemm8p<1, 2, 4, true, 3><<<dim3(256), dim3(512), 0, stream>>>(
        H1R, nullptr, W2RT, nullptr, nullptr, nullptr, 0, 512, s512, w3r, out_inv);
    // lat L2 (split): -> H2L hi/lo (silu)   [after fused ro-L2: H2Llo aliases H1R]
    gemm8p<3, 2, 4, true, 2><<<dim3(256), dim3(512), 0, stream>>>(
        H1Lhi, H1Llo, W2LThi, W2LTlo, H2Lhi, H2Llo, 512, 512, s512, nullptr, nullptr);
    // lat L3: [32768,512] @ [512,128] -> WGT f32.  NF=1, GX=2 -> grid 256 (full GPU);
    // the 2 col-blocks sharing an A-panel are XCD-adjacent -> A re-read is an L2 hit.
    gemm8p<3, 2, 1, false, 0><<<dim3(256), dim3(512), 0, stream>>>(
        H2Lhi, H2Llo, W3LThi, W3LTlo, WGT, nullptr, 128, 512, s512, nullptr, nullptr);
    // equivariant epilogue (standalone, R2-verified)
    eq_kernel<<<dim3(512), dim3(256), 0, stream>>>(eqf, WGT, typs, bond, out_eq);
}

// Round 10
// 190.564 us; speedup vs baseline: 1.3199x; 1.0312x over previous
//
#include <hip/hip_runtime.h>
#include <hip/hip_bf16.h>

#define N_ATOMS 32768

typedef __attribute__((ext_vector_type(4))) float f32x4;
typedef __attribute__((ext_vector_type(8))) short bf16x8;
typedef unsigned short u16;

__device__ __forceinline__ u16 f2b(float f) {
    union { __hip_bfloat16 b; u16 u; } c;
    c.b = __float2bfloat16(f);
    return c.u;
}
__device__ __forceinline__ float b2f(u16 u) {
    union { unsigned int i; float f; } c;
    c.i = ((unsigned int)u) << 16;
    return c.f;
}

#define GLDS16(src, dst) __builtin_amdgcn_global_load_lds( \
    (const __attribute__((address_space(1))) void*)(src),  \
    (__attribute__((address_space(3))) void*)(dst), 16, 0, 0)

// ---------------- merged setup kernel: convx + convw + zero(out_inv) ----------------
__global__ void __launch_bounds__(256) setup_kernel(
        const float* __restrict__ x, u16* __restrict__ xhi, u16* __restrict__ xlo,
        const float* __restrict__ w1l, const float* __restrict__ w2l,
        const float* __restrict__ w3l, const float* __restrict__ w1r,
        const float* __restrict__ w2r,
        u16* __restrict__ W1LThi, u16* __restrict__ W1LTlo, u16* __restrict__ W1RT,
        u16* __restrict__ W2LThi, u16* __restrict__ W2LTlo, u16* __restrict__ W2RT,
        u16* __restrict__ W3LThi, u16* __restrict__ W3LTlo,
        float* __restrict__ out_inv) {
    int bid = blockIdx.x;
    if (bid < 4096) {
        // convx: inv_features f32 [32768,256] -> split bf16 hi/lo, 8 elems/thread
        size_t i = (size_t)(bid * 256 + threadIdx.x) * 8;
        float4 v0 = *(const float4*)(x + i);
        float4 v1 = *(const float4*)(x + i + 4);
        float v[8] = {v0.x, v0.y, v0.z, v0.w, v1.x, v1.y, v1.z, v1.w};
        bf16x8 rh, rl;
#pragma unroll
        for (int j = 0; j < 8; ++j) {
            u16 h = f2b(v[j]);
            rh[j] = (short)h;
            rl[j] = (short)f2b(v[j] - b2f(h));
        }
        *(bf16x8*)(xhi + i) = rh;
        *(bf16x8*)(xlo + i) = rl;
    } else if (bid < 7424) {
        int i = (bid - 4096) * 256 + threadIdx.x;
        if (i < 131072) {                       // w1_lat [256,512] -> [512][256] hi/lo
            int n = i >> 8, k = i & 255;
            float v = w1l[k * 512 + n];
            u16 h = f2b(v);
            W1LThi[i] = h;
            W1LTlo[i] = f2b(v - b2f(h));
        } else if (i < 262144) {                // w1_ro -> [512][256] bf16
            int j = i - 131072;
            int n = j >> 8, k = j & 255;
            W1RT[j] = f2b(w1r[k * 512 + n]);
        } else if (i < 524288) {                // w2_lat [512,512] -> hi/lo
            int j = i - 262144;
            int n = j >> 9, k = j & 511;
            float v = w2l[k * 512 + n];
            u16 h = f2b(v);
            W2LThi[j] = h;
            W2LTlo[j] = f2b(v - b2f(h));
        } else if (i < 786432) {                // w2_ro -> bf16
            int j = i - 524288;
            int n = j >> 9, k = j & 511;
            W2RT[j] = f2b(w2r[k * 512 + n]);
        } else if (i < 851968) {                // w3_lat [512,128] -> [128][512] hi/lo
            int j = i - 786432;
            int n = j >> 9, k = j & 511;
            float v = w3l[k * 128 + n];
            u16 h = f2b(v);
            W3LThi[j] = h;
            W3LTlo[j] = f2b(v - b2f(h));
        }
    } else {
        // zero out_inv (d_out is not re-poisoned between graph replays)
        int i = (bid - 7424) * 256 + threadIdx.x;   // 16384 threads x 4 floats
        *(float4*)(out_inv + i * 4) = float4{0.f, 0.f, 0.f, 0.f};
    }
}

// ---------------- 256-row 8-wave MFMA GEMM body (R4/R7/R9-proven schedule) ----------------
// C = act( scale * sum_seg Aseg @ Bseg^T ).  BM=256, BN=NF*64, BK=64,
// 512 threads = 8 waves (2M x 4N), per-wave 128 x NF*16 output (acc[8][NF]).
// Per K-tile: 2 phases {ds_read frags | stage half of next tile | lgkmcnt(0)
// | setprio(1) MFMA setprio(0)}, then vmcnt(0)+barrier.
// NSEG=3: K-segments (Ahi,Bhi),(Alo,Bhi),(Ahi,Blo) = split-bf16 ~f32 precision.
// OUTK: 0 = f32, 1 = bf16, 2 = split hi/lo bf16,
//       3 = fused invout (dot w3_ro -> atomicAdd e_out, nothing else stored).
template<int NSEG, int NF, bool SILU, int OUTK>
__device__ __forceinline__ void gemm_body(
        u16* __restrict__ smem,
        const u16* __restrict__ Ahi, const u16* __restrict__ Alo,
        const u16* __restrict__ Bhi, const u16* __restrict__ Blo,
        void* __restrict__ Chi, void* __restrict__ Clo,
        int ldc, int K, float scale,
        const float* __restrict__ e_w3, float* __restrict__ e_out,
        int bid, int nwg, int GX) {
    constexpr int LBSZ = NF * 64 * 64;      // u16 per B buffer
    u16* const lA0 = smem;                  // 2 x 16384
    u16* const lB0 = smem + 32768;          // 2 x LBSZ
    const int tid = threadIdx.x;
    const int lane = tid & 63;
    const int wid = tid >> 6;
    const int wm = wid >> 2;            // 0..1 -> 128-row half
    const int wn = wid & 3;             // 0..3 -> NF*16-col quarter
    const int rlane = lane & 15;
    const int kc = lane >> 4;           // 0..3
    const int cps = rlane & 7;
    const int srow = tid >> 3;          // 0..63
    const int scp = tid & 7;

    // bijective XCD swizzle (nwg % 8 == 0)
    const int wg = (bid & 7) * (nwg >> 3) + (bid >> 3);
    const int bn = (wg % GX) * (NF * 64);
    const int bm = (wg / GX) * 256;

    const int kt = K >> 6;
    const int NT = NSEG * kt;

    auto stageA = [&](int t, int buf) {
        int seg = (NSEG == 1) ? 0 : ((t >= kt) + (t >= 2 * kt));
        const u16* As = (NSEG == 1) ? Ahi : (seg == 1 ? Alo : Ahi);
        int k0 = (t - seg * kt) << 6;
        u16* la = lA0 + buf * 16384;
#pragma unroll
        for (int call = 0; call < 4; ++call) {
            int row = call * 64 + srow;
            int c = scp ^ (row & 7);    // pre-swizzled global source, linear LDS dest
            GLDS16(As + (size_t)(bm + row) * K + k0 + c * 8, la + (size_t)(row * 64 + scp * 8));
        }
    };
    auto stageB = [&](int t, int buf) {
        int seg = (NSEG == 1) ? 0 : ((t >= kt) + (t >= 2 * kt));
        const u16* Bs = (NSEG == 1) ? Bhi : (seg == 2 ? Blo : Bhi);
        int k0 = (t - seg * kt) << 6;
        u16* lb = lB0 + buf * LBSZ;
#pragma unroll
        for (int call = 0; call < NF; ++call) {
            int row = call * 64 + srow;
            int c = scp ^ (row & 7);
            GLDS16(Bs + (size_t)(bn + row) * K + k0 + c * 8, lb + (size_t)(row * 64 + scp * 8));
        }
    };

    f32x4 acc[8][NF] = {};

    // prologue: tile 0 in flight, then sync
    stageA(0, 0);
    stageB(0, 0);
    asm volatile("s_waitcnt vmcnt(0)" ::: "memory");
    __builtin_amdgcn_s_barrier();

    for (int t = 0; t < NT; ++t) {
        const int cur = t & 1, nxt = cur ^ 1;
        const bool pf = (t + 1 < NT);
        const u16* la = lA0 + cur * 16384;
        const u16* lb = lB0 + cur * LBSZ;
#pragma unroll
        for (int ks = 0; ks < 2; ++ks) {
            bf16x8 af[8], bfr[NF];
            const int cp = (ks * 4 + kc) ^ cps;
#pragma unroll
            for (int m = 0; m < 8; ++m) {
                int row = wm * 128 + m * 16 + rlane;
                af[m] = *(const bf16x8*)&la[row * 64 + cp * 8];
            }
#pragma unroll
            for (int n = 0; n < NF; ++n) {
                int row = wn * (NF * 16) + n * 16 + rlane;
                bfr[n] = *(const bf16x8*)&lb[row * 64 + cp * 8];
            }
            if (pf) {                       // issue next tile's loads early (stay in flight)
                if (ks == 0) stageA(t + 1, nxt);
                else         stageB(t + 1, nxt);
            }
            asm volatile("s_waitcnt lgkmcnt(0)" ::: "memory");
            __builtin_amdgcn_sched_barrier(0);
            __builtin_amdgcn_s_setprio(1);
#pragma unroll
            for (int m = 0; m < 8; ++m)
#pragma unroll
                for (int n = 0; n < NF; ++n)
                    acc[m][n] = __builtin_amdgcn_mfma_f32_16x16x32_bf16(af[m], bfr[n], acc[m][n], 0, 0, 0);
            __builtin_amdgcn_s_setprio(0);
        }
        asm volatile("s_waitcnt vmcnt(0)" ::: "memory");   // next tile's loads landed
        __builtin_amdgcn_s_barrier();                      // all waves done reading cur
    }

    const int g = lane >> 4;

    if constexpr (OUTK == 3) {
        // fused invout: out[row,j] += sum_col silu(acc*scale) * w3[col,j] / sqrt(512)
        const float s512f = 0.04419417382415922f;
        float wj0[NF], wj1[NF];
#pragma unroll
        for (int n = 0; n < NF; ++n) {
            int gc = bn + wn * (NF * 16) + n * 16 + rlane;
            wj0[n] = e_w3[gc * 2] * s512f;
            wj1[n] = e_w3[gc * 2 + 1] * s512f;
        }
#pragma unroll
        for (int m = 0; m < 8; ++m)
#pragma unroll
            for (int r = 0; r < 4; ++r) {
                float s0 = 0.f, s1 = 0.f;
#pragma unroll
                for (int n = 0; n < NF; ++n) {
                    float v = acc[m][n][r] * scale;
                    v = v / (1.0f + __expf(-v));
                    s0 = fmaf(v, wj0[n], s0);
                    s1 = fmaf(v, wj1[n], s1);
                }
#pragma unroll
                for (int off = 1; off < 16; off <<= 1) {
                    s0 += __shfl_xor(s0, off);
                    s1 += __shfl_xor(s1, off);
                }
                if (rlane == 0) {
                    int row = bm + wm * 128 + m * 16 + g * 4 + r;
                    atomicAdd(&e_out[row * 2], s0);
                    atomicAdd(&e_out[row * 2 + 1], s1);
                }
            }
    } else {
        // standard epilogue: C/D layout col = lane&15, row = (lane>>4)*4 + reg
#pragma unroll
        for (int m = 0; m < 8; ++m) {
            int grow0 = bm + wm * 128 + m * 16 + (g << 2);
#pragma unroll
            for (int n = 0; n < NF; ++n) {
                int gcol = bn + wn * (NF * 16) + n * 16 + rlane;
#pragma unroll
                for (int r = 0; r < 4; ++r) {
                    float v = acc[m][n][r] * scale;
                    if constexpr (SILU) v = v / (1.0f + __expf(-v));
                    size_t idx = (size_t)(grow0 + r) * ldc + gcol;
                    if constexpr (OUTK == 0) {
                        ((float*)Chi)[idx] = v;
                    } else if constexpr (OUTK == 1) {
                        ((u16*)Chi)[idx] = f2b(v);
                    } else {
                        u16 h = f2b(v);
                        ((u16*)Chi)[idx] = h;
                        ((u16*)Clo)[idx] = f2b(v - b2f(h));
                    }
                }
            }
        }
    }
}

// ---------------- merged GEMM dispatches ----------------
static constexpr float S256 = 0.0625f;                 // 1/sqrt(256)
static constexpr float S512 = 0.04419417382415922f;    // 1/sqrt(512)

// L1: blocks 0-255 = lat (split, NT=12), 256-511 = ro (bf16, NT=4, backfills tails)
__global__ void __launch_bounds__(512, 2) gemm_l1(
        const u16* __restrict__ XHI, const u16* __restrict__ XLO,
        const u16* __restrict__ W1LThi, const u16* __restrict__ W1LTlo,
        const u16* __restrict__ W1RT,
        u16* __restrict__ H1Lhi, u16* __restrict__ H1Llo, u16* __restrict__ H1R) {
    __shared__ __align__(16) u16 smem[65536];
    int bid = blockIdx.x;
    if (bid < 256)
        gemm_body<3, 4, true, 2>(smem, XHI, XLO, W1LThi, W1LTlo, H1Lhi, H1Llo,
                                 512, 256, S256, nullptr, nullptr, bid, 256, 2);
    else
        gemm_body<1, 4, true, 1>(smem, XHI, nullptr, W1RT, nullptr, H1R, nullptr,
                                 512, 256, S256, nullptr, nullptr, bid - 256, 256, 2);
}

// L2: blocks 0-255 = lat (split, NT=24), 256-511 = ro+invout fused (NT=8)
__global__ void __launch_bounds__(512, 2) gemm_l2(
        const u16* __restrict__ H1Lhi, const u16* __restrict__ H1Llo,
        const u16* __restrict__ W2LThi, const u16* __restrict__ W2LTlo,
        const u16* __restrict__ H1R, const u16* __restrict__ W2RT,
        u16* __restrict__ H2Lhi, u16* __restrict__ H2Llo,
        const float* __restrict__ w3r, float* __restrict__ out_inv) {
    __shared__ __align__(16) u16 smem[65536];
    int bid = blockIdx.x;
    if (bid < 256)
        gemm_body<3, 4, true, 2>(smem, H1Lhi, H1Llo, W2LThi, W2LTlo, H2Lhi, H2Llo,
                                 512, 512, S512, nullptr, nullptr, bid, 256, 2);
    else
        gemm_body<1, 4, true, 3>(smem, H1R, nullptr, W2RT, nullptr, nullptr, nullptr,
                                 0, 512, S512, w3r, out_inv, bid - 256, 256, 2);
}

// L3: [32768,512] @ [512,128] -> WGT f32.  NF=1, GX=2 -> grid 256 (full GPU),
// LDS 80KB -> 2 blocks/CU possible; A-panel re-read is an L2 hit (XCD-adjacent).
__global__ void __launch_bounds__(512, 2) gemm_l3(
        const u16* __restrict__ H2Lhi, const u16* __restrict__ H2Llo,
        const u16* __restrict__ W3LThi, const u16* __restrict__ W3LTlo,
        float* __restrict__ WGT) {
    __shared__ __align__(16) u16 smem[40960];   // 32768 A + 2*4096 B
    gemm_body<3, 1, false, 0>(smem, H2Lhi, H2Llo, W3LThi, W3LTlo, WGT, nullptr,
                              128, 512, S512, nullptr, nullptr, (int)blockIdx.x, 256, 2);
}

// ---------------- per-atom equivariant output (R2-verified) ----------------
__global__ void eq_kernel(const float* __restrict__ eqf, const float* __restrict__ wgt,
                          const int* __restrict__ types, const float* __restrict__ bond,
                          float* __restrict__ out) {
    int t = blockIdx.x * 256 + threadIdx.x;   // 131072 = 32768*4
    int n = t >> 2, v = t & 3;
    const float* e = eqf + (size_t)n * 96;
    const float* w = wgt + (size_t)n * 128 + v;
    float a0 = 0.f, a1 = 0.f, a2 = 0.f;
#pragma unroll
    for (int u = 0; u < 32; ++u) {
        float wv = w[u * 4];
        a0 = fmaf(e[u * 3 + 0], wv, a0);
        a1 = fmaf(e[u * 3 + 1], wv, a1);
        a2 = fmaf(e[u * 3 + 2], wv, a2);
    }
    const float s = 0.17677669529663687f;   // 1/sqrt(32)
    a0 *= s; a1 *= s; a2 *= s;
    float norm = sqrtf(a0 * a0 + a1 * a1 + a2 * a2) + 1e-10f;
    float bl = bond[types[n] * 4 + v];
    float r0 = a0 / norm, r1 = a1 / norm, r2 = a2 / norm;
    if (isnan(r0)) r0 = 0.f;
    if (isnan(r1)) r1 = 0.f;
    if (isnan(r2)) r2 = 0.f;
    out[(size_t)n * 12 + v * 3 + 0] = r0 * bl;
    out[(size_t)n * 12 + v * 3 + 1] = r1 * bl;
    out[(size_t)n * 12 + v * 3 + 2] = r2 * bl;
}

// ---------------- launcher ----------------
extern "C" void kernel_launch(void* const* d_in, const int* in_sizes, int n_in,
                              void* d_out, int out_size, void* d_ws, size_t ws_size,
                              hipStream_t stream) {
    const float* inv  = (const float*)d_in[0];
    const float* eqf  = (const float*)d_in[1];
    const int*   typs = (const int*)d_in[2];
    const float* w1l  = (const float*)d_in[3];
    const float* w2l  = (const float*)d_in[4];
    const float* w3l  = (const float*)d_in[5];
    const float* w1r  = (const float*)d_in[6];
    const float* w2r  = (const float*)d_in[7];
    const float* w3r  = (const float*)d_in[8];
    const float* bond = (const float*)d_in[9];

    char* ws = (char*)d_ws;
    const size_t MB = 1024 * 1024, KB = 1024;
    // memory map (re-derived for merged dispatches; no intra-dispatch aliasing):
    u16* XHI   = (u16*)(ws);             // 16MB [32768][256]   dead after GEMM1
    u16* XLO   = (u16*)(ws + 16 * MB);   // 16MB                dead after GEMM1
    u16* H1R   = (u16*)(ws + 32 * MB);   // 32MB [32768][512]   dead after GEMM2
    u16* H1Lhi = (u16*)(ws + 64 * MB);   // 32MB                dead after GEMM2
    u16* H1Llo = (u16*)(ws + 96 * MB);   // 32MB                dead after GEMM2
    u16* H2Lhi = (u16*)(ws);             // 32MB, over XHI+XLO (dead)
    u16* H2Llo = (u16*)(ws + 128 * MB);  // 32MB fresh
    float* WGT = (float*)(ws + 32 * MB); // 16MB, over H1R (dead when GEMM3 writes)
    char* wb = ws + 160 * MB;
    u16* W1LThi = (u16*)(wb);               // 256KB [512][256]
    u16* W1LTlo = (u16*)(wb + 256 * KB);    // 256KB
    u16* W1RT   = (u16*)(wb + 512 * KB);    // 256KB
    u16* W2LThi = (u16*)(wb + 768 * KB);    // 512KB [512][512]
    u16* W2LTlo = (u16*)(wb + 1280 * KB);   // 512KB
    u16* W2RT   = (u16*)(wb + 1792 * KB);   // 512KB
    u16* W3LThi = (u16*)(wb + 2304 * KB);   // 128KB [128][512]
    u16* W3LTlo = (u16*)(wb + 2432 * KB);   // 128KB

    float* out_inv = (float*)d_out;                 // [32768][2]
    float* out_eq  = (float*)d_out + N_ATOMS * 2;   // [32768][4][3]

    // 1. setup: convx + convw + zero(out_inv)
    setup_kernel<<<dim3(7488), dim3(256), 0, stream>>>(
        inv, XHI, XLO, w1l, w2l, w3l, w1r, w2r,
        W1LThi, W1LTlo, W1RT, W2LThi, W2LTlo, W2RT, W3LThi, W3LTlo, out_inv);
    // 2. L1 merged: lat (split) -> H1L hi/lo ; ro -> H1R
    gemm_l1<<<dim3(512), dim3(512), 0, stream>>>(
        XHI, XLO, W1LThi, W1LTlo, W1RT, H1Lhi, H1Llo, H1R);
    // 3. L2 merged: lat (split) -> H2L hi/lo ; ro+invout -> atomics into out_inv
    gemm_l2<<<dim3(512), dim3(512), 0, stream>>>(
        H1Lhi, H1Llo, W2LThi, W2LTlo, H1R, W2RT, H2Lhi, H2Llo, w3r, out_inv);
    // 4. L3: lat (split) -> WGT f32
    gemm_l3<<<dim3(256), dim3(512), 0, stream>>>(H2Lhi, H2Llo, W3LThi, W3LTlo, WGT);
    // 5. equivariant epilogue
    eq_kernel<<<dim3(512), dim3(256), 0, stream>>>(eqf, WGT, typs, bond, out_eq);
}